// Round 4
// baseline (75.653 us; speedup 1.0000x reference)
//
#include <hip/hip_runtime.h>

// EmbeddingGrad_48137993454109
// Reference: out[b,l,d] = W[d, idx[b,l]] + bias[d]
//   idx : int32 [1024,50]          (in[0], 51200 elems)
//   W   : f32   [128, 8192]        (in[1], 1048576 elems)
//   b   : f32   [128]              (in[2])
//   out : f32   [1024,50,128]      (6553600 elems)
//
// Strategy (memory-bound):
//   K1: transpose W into ws as Wt[v][d] = W[d][v] + b[d]  (4 MB, LDS-tiled,
//       bias folded so K2 is a pure gather-copy)
//   K2: out row (512 B) = Wt row (512 B), float4 per lane, 32 lanes/row,
//       fully coalesced reads and writes. Wt (4 MB) stays hot in L2/L3.

#define VOCAB 8192
#define DIM   128
#define NROWS (1024 * 50)   // 51200 output rows

__global__ __launch_bounds__(256)
void transpose_bias_kernel(const float* __restrict__ W,
                           const float* __restrict__ bias,
                           float* __restrict__ Wt) {
    // 64x64 tile; +1 pad keeps LDS reads at 2-way (free) aliasing
    __shared__ float tile[64][65];
    const int v0 = blockIdx.x * 64;   // vocab offset
    const int d0 = blockIdx.y * 64;   // dim offset (0 or 64)
    const int tx = threadIdx.x & 63;
    const int ty = threadIdx.x >> 6;  // 0..3

    // Coalesced read: W[d0+d][v0+tx], consecutive lanes -> consecutive v
#pragma unroll
    for (int i = 0; i < 16; ++i) {
        const int d = ty + 4 * i;
        tile[d][tx] = W[(size_t)(d0 + d) * VOCAB + (v0 + tx)];
    }
    __syncthreads();

    const float bv = bias[d0 + tx];
    // Coalesced write: Wt[v0+v][d0+tx], consecutive lanes -> consecutive d
#pragma unroll
    for (int i = 0; i < 16; ++i) {
        const int v = ty + 4 * i;
        Wt[(size_t)(v0 + v) * DIM + (d0 + tx)] = tile[tx][v] + bv;
    }
}

__global__ __launch_bounds__(256)
void gather_rows_kernel(const int* __restrict__ idx,
                        const float4* __restrict__ Wt4,
                        float4* __restrict__ out4) {
    // one float4 per thread; 32 threads cover one 128-float output row
    const int t   = blockIdx.x * 256 + threadIdx.x;  // 0 .. NROWS*32-1
    const int row = t >> 5;
    const int q   = t & 31;
    const int v   = idx[row];                        // 32-way broadcast load
    out4[t] = Wt4[(size_t)v * 32 + q];
}

extern "C" void kernel_launch(void* const* d_in, const int* in_sizes, int n_in,
                              void* d_out, int out_size, void* d_ws, size_t ws_size,
                              hipStream_t stream) {
    const int*   idx  = (const int*)d_in[0];
    const float* W    = (const float*)d_in[1];
    const float* bias = (const float*)d_in[2];
    float*       out  = (float*)d_out;
    float*       Wt   = (float*)d_ws;   // 8192*128*4 = 4 MB scratch

    dim3 tgrid(VOCAB / 64, DIM / 64);   // (128, 2)
    transpose_bias_kernel<<<tgrid, 256, 0, stream>>>(W, bias, Wt);

    const int total4 = NROWS * (DIM / 4);          // 1,638,400 float4s
    gather_rows_kernel<<<total4 / 256, 256, 0, stream>>>(
        idx, (const float4*)Wt, (float4*)out);
}